// Round 9
// baseline (907.894 us; speedup 1.0000x reference)
//
#include <hip/hip_runtime.h>

#define NN 100000
#define CIN 500
#define KPAD 512
#define HID 256
#define COUT 50
#define NPADOUT 64
#define FPAD 64                        // padded feature-row length for x_k (128 B)

#define NBLK 256                       // edge-chunk blocks for P1/P2
#define CB 128                         // nodes per coarse bucket
#define NC ((NN + CB - 1) / CB)        // 782 coarse buckets
#define NCB (NC * NBLK)                // per-(bucket,block) counts
#define NCB2 (2 * NCB)                 // dst + src parts

typedef __attribute__((ext_vector_type(8))) short short8;
typedef __attribute__((ext_vector_type(4))) float f32x4;

static __device__ __forceinline__ unsigned short f2bf(float f) {
  union { float f; unsigned u; } v; v.f = f;
  unsigned r = (v.u + 0x7fffu + ((v.u >> 16) & 1u)) >> 16;
  return (unsigned short)r;
}

static __device__ __forceinline__ int slotAt(const int* __restrict__ incl,
                                             const int* __restrict__ bpre, int g) {
  return g ? incl[g - 1] + bpre[(g - 1) >> 10] : 0;
}

// ---------------- build P1: coarse histograms (src & dst), LDS-privatized ----------------

__launch_bounds__(256)
__global__ void k_p1(const int* __restrict__ src, const int* __restrict__ dst,
                     int* __restrict__ blk_cnt, int E, int chunk) {
  __shared__ int bd[NC], bs[NC];
  int tid = threadIdx.x;
  for (int i = tid; i < NC; i += 256) { bd[i] = 0; bs[i] = 0; }
  __syncthreads();
  int e0 = blockIdx.x * chunk, e1 = min(E, e0 + chunk);
  for (int e = e0 + tid; e < e1; e += 256) {
    atomicAdd(&bd[dst[e] >> 7], 1);
    atomicAdd(&bs[src[e] >> 7], 1);
  }
  __syncthreads();
  for (int i = tid; i < NC; i += 256) {
    blk_cnt[i * NBLK + blockIdx.x] = bd[i];
    blk_cnt[NCB + i * NBLK + blockIdx.x] = bs[i];
  }
}

// ---------------- scan over NCB2 counts ----------------

__global__ void k_scan_a(const int* __restrict__ hist, int* __restrict__ incl,
                         int* __restrict__ bsum, int n) {
  __shared__ int ts[256];
  int tid = threadIdx.x;
  int base = blockIdx.x * 1024 + tid * 4;
  int a0 = 0, a1 = 0, a2 = 0, a3 = 0;
  if (base + 3 < n) {
    a0 = hist[base]; a1 = hist[base + 1]; a2 = hist[base + 2]; a3 = hist[base + 3];
  } else {
    if (base     < n) a0 = hist[base];
    if (base + 1 < n) a1 = hist[base + 1];
    if (base + 2 < n) a2 = hist[base + 2];
    if (base + 3 < n) a3 = hist[base + 3];
  }
  a1 += a0; a2 += a1; a3 += a2;
  ts[tid] = a3;
  __syncthreads();
  for (int o = 1; o < 256; o <<= 1) {
    int v = ts[tid];
    if (tid >= o) v += ts[tid - o];
    __syncthreads();
    ts[tid] = v;
    __syncthreads();
  }
  int ex = tid ? ts[tid - 1] : 0;
  if (base     < n) incl[base]     = a0 + ex;
  if (base + 1 < n) incl[base + 1] = a1 + ex;
  if (base + 2 < n) incl[base + 2] = a2 + ex;
  if (base + 3 < n) incl[base + 3] = a3 + ex;
  if (tid == 255) bsum[blockIdx.x] = ts[255];
}

__global__ void k_scan_b(const int* __restrict__ bsum, int* __restrict__ bpre, int nb) {
  __shared__ int s[512];
  int tid = threadIdx.x;
  s[tid] = (tid < nb) ? bsum[tid] : 0;
  __syncthreads();
  for (int o = 1; o < 512; o <<= 1) {
    int v = s[tid];
    if (tid >= o) v += s[tid - o];
    __syncthreads();
    s[tid] = v;
    __syncthreads();
  }
  if (tid < nb) bpre[tid] = tid ? s[tid - 1] : 0;
}

// ---------------- build P2: scatter edges into coarse buckets (no global atomics) ----------------

__launch_bounds__(256)
__global__ void k_p2(const int* __restrict__ src, const int* __restrict__ dst,
                     const int* __restrict__ incl, const int* __restrict__ bpre,
                     int* __restrict__ pkd, unsigned char* __restrict__ pks, int E, int chunk) {
  __shared__ int cd[NC], cs[NC];
  int tid = threadIdx.x;
  for (int i = tid; i < NC; i += 256) {
    cd[i] = slotAt(incl, bpre, i * NBLK + blockIdx.x);
    cs[i] = slotAt(incl, bpre, NCB + i * NBLK + blockIdx.x) - E;
  }
  __syncthreads();
  int e0 = blockIdx.x * chunk, e1 = min(E, e0 + chunk);
  for (int e = e0 + tid; e < e1; e += 256) {
    int s = src[e], d = dst[e];
    int pd = atomicAdd(&cd[d >> 7], 1);
    pkd[pd] = (s << 7) | (d & 127);
    int ps = atomicAdd(&cs[s >> 7], 1);
    pks[ps] = (unsigned char)(s & 127);
  }
}

// ---------------- build P3s: fine histogram of src -> dinv ----------------

__launch_bounds__(256)
__global__ void k_p3s(const int* __restrict__ incl, const int* __restrict__ bpre,
                      const unsigned char* __restrict__ pks, float* __restrict__ dinv, int E) {
  __shared__ int hist[CB];
  int b = blockIdx.x, tid = threadIdx.x;
  if (tid < CB) hist[tid] = 0;
  __syncthreads();
  int s0 = slotAt(incl, bpre, NCB + b * NBLK) - E;
  int s1 = slotAt(incl, bpre, NCB + (b + 1) * NBLK) - E;
  for (int e = s0 + tid; e < s1; e += 256) atomicAdd(&hist[pks[e]], 1);
  __syncthreads();
  if (tid < CB) {
    int node = b * CB + tid;
    if (node < NN) {
      int c = hist[tid];
      dinv[node] = c > 0 ? rsqrtf((float)c) : 0.f;
    }
  }
}

// ---------------- build P3d: fine sort by dst -> offs + interleaved (src,norm) CSR ----------

__launch_bounds__(256)
__global__ void k_p3d(const int* __restrict__ incl, const int* __restrict__ bpre,
                      const int* __restrict__ pkd, const float* __restrict__ dinv,
                      int* __restrict__ offs, int2* __restrict__ epk, int E) {
  __shared__ int hist[CB], base[CB], cur[CB];
  int b = blockIdx.x, tid = threadIdx.x;
  if (tid < CB) hist[tid] = 0;
  __syncthreads();
  int s0 = slotAt(incl, bpre, b * NBLK);
  int s1 = slotAt(incl, bpre, (b + 1) * NBLK);
  for (int e = s0 + tid; e < s1; e += 256) atomicAdd(&hist[pkd[e] & 127], 1);
  __syncthreads();
  if (tid == 0) {
    int acc = s0;
    for (int i = 0; i < CB; i++) { base[i] = acc; cur[i] = acc; acc += hist[i]; }
  }
  __syncthreads();
  if (tid < CB) {
    int node = b * CB + tid;
    if (node < NN) offs[node] = base[tid];
  }
  if (b == gridDim.x - 1 && tid == 0) offs[NN] = E;
  for (int e = s0 + tid; e < s1; e += 256) {
    int pk = pkd[e];
    int fine = pk & 127, s = pk >> 7;
    int pos = atomicAdd(&cur[fine], 1);
    float nm = dinv[s] * dinv[b * CB + fine];
    epk[pos] = make_int2(s, __float_as_int(nm));
  }
}

// ---------------- weight transpose+convert (merged) ----------------

__global__ void k_wt(const float* __restrict__ W1, const float* __restrict__ W2,
                     unsigned short* __restrict__ W1T, unsigned short* __restrict__ W2T) {
  int idx = blockIdx.x * 256 + threadIdx.x;
  if (idx < HID * KPAD) {
    int n = idx >> 9, k = idx & 511;
    W1T[idx] = (k < CIN) ? f2bf(W1[(long)k * HID + n]) : (unsigned short)0;
  } else if (idx < HID * KPAD + NPADOUT * HID) {
    int i2 = idx - HID * KPAD;
    int n = i2 >> 8, k = i2 & 255;
    W2T[i2] = (n < COUT) ? f2bf(W2[(long)k * COUT + n]) : (unsigned short)0;
  }
}

// ---------------- fused MLP (R5 distance-2 prefetch; R7: HIDB write removed) --------------

#define LOADS(ra0_, ra1_, rb0_, rb1_, kkc)                                        \
  {                                                                               \
    const int kk_ = (kkc);                                                        \
    bool okk = kk_ + sc * 4 <= 496;                                               \
    if (okA && okk) ra0_ = *reinterpret_cast<const float4*>(&X[xbaseA + kk_]);    \
    else { ra0_.x = ra0_.y = ra0_.z = ra0_.w = 0.f; }                             \
    if (okB && okk) ra1_ = *reinterpret_cast<const float4*>(&X[xbaseB + kk_]);    \
    else { ra1_.x = ra1_.y = ra1_.z = ra1_.w = 0.f; }                             \
    rb0_ = *reinterpret_cast<const uint4*>(&W1T[wbase0 + kk_]);                   \
    rb1_ = *reinterpret_cast<const uint4*>(&W1T[wbase1 + kk_]);                   \
  }

#define STORE_LDS(As_, Bs_, ra0_, ra1_, rb0_, rb1_)                               \
  {                                                                               \
    ushort4 v0, v1;                                                               \
    v0.x = f2bf(ra0_.x); v0.y = f2bf(ra0_.y); v0.z = f2bf(ra0_.z); v0.w = f2bf(ra0_.w); \
    v1.x = f2bf(ra1_.x); v1.y = f2bf(ra1_.y); v1.z = f2bf(ra1_.z); v1.w = f2bf(ra1_.w); \
    *reinterpret_cast<ushort4*>(&As_[sr * 40 + sc * 4]) = v0;                     \
    *reinterpret_cast<ushort4*>(&As_[(sr + 64) * 40 + sc * 4]) = v1;              \
    *reinterpret_cast<uint4*>(&Bs_[br * 40 + bc * 8]) = rb0_;                     \
    *reinterpret_cast<uint4*>(&Bs_[(br + 128) * 40 + bc * 8]) = rb1_;             \
  }

#define COMPUTE(As_, Bs_)                                                         \
  {                                                                               \
    short8 af[4], bfr[4];                                                         \
    const int koff = (lane >> 4) * 8;                                             \
    _Pragma("unroll")                                                             \
    for (int i = 0; i < 4; i++)                                                   \
      af[i] = *reinterpret_cast<const short8*>(&As_[(wr * 64 + i * 16 + (lane & 15)) * 40 + koff]); \
    _Pragma("unroll")                                                             \
    for (int j = 0; j < 4; j++)                                                   \
      bfr[j] = *reinterpret_cast<const short8*>(&Bs_[(wc * 64 + j * 16 + (lane & 15)) * 40 + koff]); \
    _Pragma("unroll")                                                             \
    for (int i = 0; i < 4; i++)                                                   \
      _Pragma("unroll")                                                           \
      for (int j = 0; j < 4; j++)                                                 \
        acc[i][j] = __builtin_amdgcn_mfma_f32_16x16x32_bf16(af[i], bfr[j], acc[i][j], 0, 0, 0); \
  }

__launch_bounds__(512)
__global__ void k_mlp(const float* __restrict__ X, const unsigned short* __restrict__ W1T,
                      const float* __restrict__ b1, const unsigned short* __restrict__ W2T,
                      const float* __restrict__ b2, unsigned short* __restrict__ X0B) {
  __shared__ unsigned short smem[2 * 15360];
  const int tid = threadIdx.x;
  const int lane = tid & 63, w = tid >> 6;
  const int wr = w >> 2, wc = w & 3;
  const int row0 = blockIdx.x * 128;
  f32x4 acc[4][4] = {};
  const int sr = tid >> 3, sc = tid & 7;
  const int br = tid >> 2, bc = tid & 3;

  float4 raA0, raA1; uint4 rbA0, rbA1;
  float4 raB0, raB1; uint4 rbB0, rbB1;

  const int growA = row0 + sr;
  const int growB = row0 + sr + 64;
  const bool okA = growA < NN, okB = growB < NN;
  const long xbaseA = (long)growA * CIN + sc * 4;
  const long xbaseB = (long)growB * CIN + sc * 4;
  const long wbase0 = (long)br * KPAD + bc * 8;
  const long wbase1 = (long)(br + 128) * KPAD + bc * 8;

  LOADS(raA0, raA1, rbA0, rbA1, 0);
  LOADS(raB0, raB1, rbB0, rbB1, 32);

#pragma unroll
  for (int tt = 0; tt < 8; tt++) {
    const int kk0 = tt * 64;
    {   // even step: buf0, set A
      unsigned short* As = smem;
      unsigned short* Bs = smem + 128 * 40;
      STORE_LDS(As, Bs, raA0, raA1, rbA0, rbA1);
      __syncthreads();
      if (kk0 + 64 < KPAD) LOADS(raA0, raA1, rbA0, rbA1, kk0 + 64);
      COMPUTE(As, Bs);
    }
    {   // odd step: buf1, set B
      unsigned short* As = smem + 15360;
      unsigned short* Bs = As + 128 * 40;
      STORE_LDS(As, Bs, raB0, raB1, rbB0, rbB1);
      __syncthreads();
      if (kk0 + 96 < KPAD) LOADS(raB0, raB1, rbB0, rbB1, kk0 + 96);
      COMPUTE(As, Bs);
    }
  }

  // ---- epilogue: two 64-row phases through LDS, then h @ W2 ----
  unsigned short* Hs = smem;                    // 64 rows x 264 (stride pad)
  const int rt = w >> 1;
  const int jh = w & 1;
#pragma unroll
  for (int ph = 0; ph < 2; ph++) {
    __syncthreads();
    if (wr == ph) {
#pragma unroll
      for (int i = 0; i < 4; i++) {
        int lr = i * 16 + (lane >> 4) * 4;
#pragma unroll
        for (int j = 0; j < 4; j++) {
          int col = wc * 64 + j * 16 + (lane & 15);
          float bv = b1[col];
#pragma unroll
          for (int r = 0; r < 4; r++) {
            float v = acc[i][j][r] + bv;
            v = v > 0.f ? v : 0.f;
            Hs[(lr + r) * 264 + col] = f2bf(v);
          }
        }
      }
    }
    __syncthreads();
    f32x4 acc2[2] = {};
    const int koff = (lane >> 4) * 8;
    for (int kk = 0; kk < HID; kk += 32) {
      short8 a = *reinterpret_cast<const short8*>(&Hs[(rt * 16 + (lane & 15)) * 264 + kk + koff]);
#pragma unroll
      for (int jj = 0; jj < 2; jj++) {
        int n = (jh * 2 + jj) * 16 + (lane & 15);
        short8 b = *reinterpret_cast<const short8*>(&W2T[n * HID + kk + koff]);
        acc2[jj] = __builtin_amdgcn_mfma_f32_16x16x32_bf16(a, b, acc2[jj], 0, 0, 0);
      }
    }
#pragma unroll
    for (int jj = 0; jj < 2; jj++) {
      int col = (jh * 2 + jj) * 16 + (lane & 15);
      float bv = (col < COUT) ? b2[col] : 0.f;  // W2T pad rows are zero -> v = 0 for pad cols
#pragma unroll
      for (int r = 0; r < 4; r++) {
        int row = row0 + ph * 64 + rt * 16 + (lane >> 4) * 4 + r;
        if (row < NN) {
          float v = acc2[jj][r] + bv;
          X0B[((long)row << 6) + col] = f2bf(v);
        }
      }
    }
  }
}

// ---------------- propagation: 4 nodes/wave, 16 lanes/node, pure gather sweep ----------
// R7/R8 (evidence: 2x gather streams gave only +6% -> wall is random-line service;
// table 12.8 MB vs 4 MB/XCD L2 -> 69% of lines fall to the slow L3 path): remove ALL
// competing L2 traffic from the sweeps. hid accumulation deferred to k_fin (archive the
// even x_2k buffers instead -- they were being written anyway); xout stores and epk
// loads are non-temporal so the single-use streams don't evict gather-table lines.
// R8 fix: nontemporal builtins reject HIP_vector_type -- go through (unsigned) long long.

__launch_bounds__(256)
__global__ void k_prop(const int* __restrict__ offs, const int2* __restrict__ epk,
                       const unsigned short* __restrict__ xin,
                       unsigned short* __restrict__ xout) {
  const long long* __restrict__ epk8 = reinterpret_cast<const long long*>(epk);
  int node = blockIdx.x * 16 + (threadIdx.x >> 4);
  if (node >= NN) return;
  int h = threadIdx.x & 15;
  int fp = h * 4;                       // first of 4 features (shorts) this lane owns
  int s0 = offs[node], s1 = offs[node + 1];
  float a0 = 0.f, a1 = 0.f, a2 = 0.f, a3 = 0.f;
  int e = s0;
  for (; e + 7 < s1; e += 8) {
    long long p[8];
#pragma unroll
    for (int q = 0; q < 8; q++) p[q] = __builtin_nontemporal_load(&epk8[e + q]);
    uint2 v[8];
#pragma unroll
    for (int q = 0; q < 8; q++)
      v[q] = *reinterpret_cast<const uint2*>(&xin[((long)(int)p[q] << 6) + fp]);
#pragma unroll
    for (int q = 0; q < 8; q++) {
      float wq = __int_as_float((int)(p[q] >> 32));
      a0 += wq * __uint_as_float(v[q].x << 16);
      a1 += wq * __uint_as_float(v[q].x & 0xffff0000u);
      a2 += wq * __uint_as_float(v[q].y << 16);
      a3 += wq * __uint_as_float(v[q].y & 0xffff0000u);
    }
  }
  for (; e + 3 < s1; e += 4) {
    long long p0 = __builtin_nontemporal_load(&epk8[e]);
    long long p1 = __builtin_nontemporal_load(&epk8[e + 1]);
    long long p2 = __builtin_nontemporal_load(&epk8[e + 2]);
    long long p3 = __builtin_nontemporal_load(&epk8[e + 3]);
    uint2 v0 = *reinterpret_cast<const uint2*>(&xin[((long)(int)p0 << 6) + fp]);
    uint2 v1 = *reinterpret_cast<const uint2*>(&xin[((long)(int)p1 << 6) + fp]);
    uint2 v2 = *reinterpret_cast<const uint2*>(&xin[((long)(int)p2 << 6) + fp]);
    uint2 v3 = *reinterpret_cast<const uint2*>(&xin[((long)(int)p3 << 6) + fp]);
    float w0 = __int_as_float((int)(p0 >> 32)), w1 = __int_as_float((int)(p1 >> 32));
    float w2 = __int_as_float((int)(p2 >> 32)), w3 = __int_as_float((int)(p3 >> 32));
    a0 += w0 * __uint_as_float(v0.x << 16) + w1 * __uint_as_float(v1.x << 16)
        + w2 * __uint_as_float(v2.x << 16) + w3 * __uint_as_float(v3.x << 16);
    a1 += w0 * __uint_as_float(v0.x & 0xffff0000u) + w1 * __uint_as_float(v1.x & 0xffff0000u)
        + w2 * __uint_as_float(v2.x & 0xffff0000u) + w3 * __uint_as_float(v3.x & 0xffff0000u);
    a2 += w0 * __uint_as_float(v0.y << 16) + w1 * __uint_as_float(v1.y << 16)
        + w2 * __uint_as_float(v2.y << 16) + w3 * __uint_as_float(v3.y << 16);
    a3 += w0 * __uint_as_float(v0.y & 0xffff0000u) + w1 * __uint_as_float(v1.y & 0xffff0000u)
        + w2 * __uint_as_float(v2.y & 0xffff0000u) + w3 * __uint_as_float(v3.y & 0xffff0000u);
  }
  for (; e < s1; e++) {
    long long p0 = __builtin_nontemporal_load(&epk8[e]);
    float w0 = __int_as_float((int)(p0 >> 32));
    uint2 v0 = *reinterpret_cast<const uint2*>(&xin[((long)(int)p0 << 6) + fp]);
    a0 += w0 * __uint_as_float(v0.x << 16);
    a1 += w0 * __uint_as_float(v0.x & 0xffff0000u);
    a2 += w0 * __uint_as_float(v0.y << 16);
    a3 += w0 * __uint_as_float(v0.y & 0xffff0000u);
  }
  // features this lane owns: fp..fp+3; COUT=50 -> h<=11 full 8B, h==12 low dword only
  unsigned d0 = ((unsigned)f2bf(a1) << 16) | (unsigned)f2bf(a0);
  unsigned d1 = ((unsigned)f2bf(a3) << 16) | (unsigned)f2bf(a2);
  if (h <= 11) {
    unsigned long long pk8 = ((unsigned long long)d1 << 32) | d0;
    __builtin_nontemporal_store(pk8,
        reinterpret_cast<unsigned long long*>(&xout[((long)node << 6) + fp]));
  } else if (h == 12) {
    __builtin_nontemporal_store(d0,
        reinterpret_cast<unsigned*>(&xout[((long)node << 6) + fp]));
  }
}

// ---------------- final: hidden = sum temp[k]*x_2k, fused log_softmax ----------------

__launch_bounds__(256)
__global__ void k_fin(const unsigned short* __restrict__ x0,
                      const unsigned short* __restrict__ x1,
                      const unsigned short* __restrict__ x2,
                      const unsigned short* __restrict__ x3,
                      const unsigned short* __restrict__ x4,
                      const unsigned short* __restrict__ x5,
                      const float* __restrict__ temp, float* __restrict__ out) {
  int node = blockIdx.x * 4 + (threadIdx.x >> 6);
  if (node >= NN) return;
  int f = threadIdx.x & 63;
  float v = -INFINITY;
  if (f < COUT) {
    long idx = ((long)node << 6) + f;
    v = temp[0] * __uint_as_float((unsigned)x0[idx] << 16)
      + temp[1] * __uint_as_float((unsigned)x1[idx] << 16)
      + temp[2] * __uint_as_float((unsigned)x2[idx] << 16)
      + temp[3] * __uint_as_float((unsigned)x3[idx] << 16)
      + temp[4] * __uint_as_float((unsigned)x4[idx] << 16)
      + temp[5] * __uint_as_float((unsigned)x5[idx] << 16);
  }
  float m = v;
#pragma unroll
  for (int o = 32; o > 0; o >>= 1) m = fmaxf(m, __shfl_xor(m, o, 64));
  float ex = (f < COUT) ? expf(v - m) : 0.f;
  float s = ex;
#pragma unroll
  for (int o = 32; o > 0; o >>= 1) s += __shfl_xor(s, o, 64);
  if (f < COUT) out[(long)node * COUT + f] = (v - m) - logf(s);
}

// ---------------- launch ----------------

extern "C" void kernel_launch(void* const* d_in, const int* in_sizes, int n_in,
                              void* d_out, int out_size, void* d_ws, size_t ws_size,
                              hipStream_t stream) {
  const float* X  = (const float*)d_in[0];
  const int* EI   = (const int*)d_in[1];
  const float* W1 = (const float*)d_in[2];
  const float* B1 = (const float*)d_in[3];
  const float* W2 = (const float*)d_in[4];
  const float* B2 = (const float*)d_in[5];
  const float* TEMP = (const float*)d_in[6];
  const int E = in_sizes[1] / 2;
  const int* src = EI;
  const int* dst = EI + E;

  char* ws = (char*)d_ws;
  size_t off = 0;
  auto alloc = [&](size_t bytes) -> void* {
    off = (off + 511) & ~(size_t)511;
    void* p = ws + off;
    off += bytes;
    return p;
  };
  unsigned short* W1T = (unsigned short*)alloc((size_t)HID * KPAD * 2);
  unsigned short* W2T = (unsigned short*)alloc((size_t)NPADOUT * HID * 2);
  unsigned short* XB[7];                 // XB[0..5] = archived even powers, XB[6] = odd tmp
  for (int i = 0; i < 7; i++) XB[i] = (unsigned short*)alloc((size_t)NN * FPAD * 2);
  float* DINV = (float*)alloc((size_t)NN * 4);
  int* OFFS   = (int*)alloc((size_t)(NN + 1) * 4);
  int* BLKC   = (int*)alloc((size_t)NCB2 * 4);
  int* INCL   = (int*)alloc((size_t)NCB2 * 4);
  int* BSUM   = (int*)alloc(512 * 4);
  int* BPRE   = (int*)alloc(512 * 4);
  int* PKD    = (int*)alloc((size_t)E * 4);
  unsigned char* PKS = (unsigned char*)alloc((size_t)E);
  int2* EPK   = (int2*)alloc((size_t)E * 8);

  const int chunk = (E + NBLK - 1) / NBLK;
  const int nsa = (NCB2 + 1023) / 1024;

  k_p1<<<NBLK, 256, 0, stream>>>(src, dst, BLKC, E, chunk);
  k_scan_a<<<nsa, 256, 0, stream>>>(BLKC, INCL, BSUM, NCB2);
  k_scan_b<<<1, 512, 0, stream>>>(BSUM, BPRE, nsa);
  k_p2<<<NBLK, 256, 0, stream>>>(src, dst, INCL, BPRE, PKD, PKS, E, chunk);
  k_p3s<<<NC, 256, 0, stream>>>(INCL, BPRE, PKS, DINV, E);
  k_p3d<<<NC, 256, 0, stream>>>(INCL, BPRE, PKD, DINV, OFFS, EPK, E);

  k_wt<<<(HID * KPAD + NPADOUT * HID + 255) / 256, 256, 0, stream>>>(W1, W2, W1T, W2T);

  k_mlp<<<(NN + 127) / 128, 512, 0, stream>>>(X, W1T, B1, W2T, B2, XB[0]);

  const int PB = (NN + 15) / 16;
  for (int k = 0; k < 5; k++) {
    k_prop<<<PB, 256, 0, stream>>>(OFFS, EPK, XB[k], XB[6]);
    k_prop<<<PB, 256, 0, stream>>>(OFFS, EPK, XB[6], XB[k + 1]);
  }
  k_fin<<<(NN + 3) / 4, 256, 0, stream>>>(XB[0], XB[1], XB[2], XB[3], XB[4], XB[5],
                                          TEMP, (float*)d_out);
}

// Round 10
// 790.515 us; speedup vs baseline: 1.1485x; 1.1485x over previous
//
#include <hip/hip_runtime.h>

#define NN 100000
#define CIN 500
#define KPAD 512
#define HID 256
#define COUT 50
#define NPADOUT 64
#define FPAD 64                        // padded feature-row length for x_k (128 B)

#define NBLK 256                       // edge-chunk blocks for P1/P2
#define CB 128                         // nodes per coarse bucket
#define NC ((NN + CB - 1) / CB)        // 782 coarse buckets
#define NCB (NC * NBLK)                // per-(bucket,block) counts
#define NCB2 (2 * NCB)                 // dst + src parts

typedef __attribute__((ext_vector_type(8))) short short8;
typedef __attribute__((ext_vector_type(4))) float f32x4;

static __device__ __forceinline__ unsigned short f2bf(float f) {
  union { float f; unsigned u; } v; v.f = f;
  unsigned r = (v.u + 0x7fffu + ((v.u >> 16) & 1u)) >> 16;
  return (unsigned short)r;
}

static __device__ __forceinline__ int slotAt(const int* __restrict__ incl,
                                             const int* __restrict__ bpre, int g) {
  return g ? incl[g - 1] + bpre[(g - 1) >> 10] : 0;
}

// ---------------- build P1: coarse histograms (src & dst), LDS-privatized ----------------

__launch_bounds__(256)
__global__ void k_p1(const int* __restrict__ src, const int* __restrict__ dst,
                     int* __restrict__ blk_cnt, int E, int chunk) {
  __shared__ int bd[NC], bs[NC];
  int tid = threadIdx.x;
  for (int i = tid; i < NC; i += 256) { bd[i] = 0; bs[i] = 0; }
  __syncthreads();
  int e0 = blockIdx.x * chunk, e1 = min(E, e0 + chunk);
  for (int e = e0 + tid; e < e1; e += 256) {
    atomicAdd(&bd[dst[e] >> 7], 1);
    atomicAdd(&bs[src[e] >> 7], 1);
  }
  __syncthreads();
  for (int i = tid; i < NC; i += 256) {
    blk_cnt[i * NBLK + blockIdx.x] = bd[i];
    blk_cnt[NCB + i * NBLK + blockIdx.x] = bs[i];
  }
}

// ---------------- scan over NCB2 counts ----------------

__global__ void k_scan_a(const int* __restrict__ hist, int* __restrict__ incl,
                         int* __restrict__ bsum, int n) {
  __shared__ int ts[256];
  int tid = threadIdx.x;
  int base = blockIdx.x * 1024 + tid * 4;
  int a0 = 0, a1 = 0, a2 = 0, a3 = 0;
  if (base + 3 < n) {
    a0 = hist[base]; a1 = hist[base + 1]; a2 = hist[base + 2]; a3 = hist[base + 3];
  } else {
    if (base     < n) a0 = hist[base];
    if (base + 1 < n) a1 = hist[base + 1];
    if (base + 2 < n) a2 = hist[base + 2];
    if (base + 3 < n) a3 = hist[base + 3];
  }
  a1 += a0; a2 += a1; a3 += a2;
  ts[tid] = a3;
  __syncthreads();
  for (int o = 1; o < 256; o <<= 1) {
    int v = ts[tid];
    if (tid >= o) v += ts[tid - o];
    __syncthreads();
    ts[tid] = v;
    __syncthreads();
  }
  int ex = tid ? ts[tid - 1] : 0;
  if (base     < n) incl[base]     = a0 + ex;
  if (base + 1 < n) incl[base + 1] = a1 + ex;
  if (base + 2 < n) incl[base + 2] = a2 + ex;
  if (base + 3 < n) incl[base + 3] = a3 + ex;
  if (tid == 255) bsum[blockIdx.x] = ts[255];
}

__global__ void k_scan_b(const int* __restrict__ bsum, int* __restrict__ bpre, int nb) {
  __shared__ int s[512];
  int tid = threadIdx.x;
  s[tid] = (tid < nb) ? bsum[tid] : 0;
  __syncthreads();
  for (int o = 1; o < 512; o <<= 1) {
    int v = s[tid];
    if (tid >= o) v += s[tid - o];
    __syncthreads();
    s[tid] = v;
    __syncthreads();
  }
  if (tid < nb) bpre[tid] = tid ? s[tid - 1] : 0;
}

// ---------------- build P2: scatter edges into coarse buckets (no global atomics) ----------------

__launch_bounds__(256)
__global__ void k_p2(const int* __restrict__ src, const int* __restrict__ dst,
                     const int* __restrict__ incl, const int* __restrict__ bpre,
                     int* __restrict__ pkd, unsigned char* __restrict__ pks, int E, int chunk) {
  __shared__ int cd[NC], cs[NC];
  int tid = threadIdx.x;
  for (int i = tid; i < NC; i += 256) {
    cd[i] = slotAt(incl, bpre, i * NBLK + blockIdx.x);
    cs[i] = slotAt(incl, bpre, NCB + i * NBLK + blockIdx.x) - E;
  }
  __syncthreads();
  int e0 = blockIdx.x * chunk, e1 = min(E, e0 + chunk);
  for (int e = e0 + tid; e < e1; e += 256) {
    int s = src[e], d = dst[e];
    int pd = atomicAdd(&cd[d >> 7], 1);
    pkd[pd] = (s << 7) | (d & 127);
    int ps = atomicAdd(&cs[s >> 7], 1);
    pks[ps] = (unsigned char)(s & 127);
  }
}

// ---------------- build P3s: fine histogram of src -> dinv ----------------

__launch_bounds__(256)
__global__ void k_p3s(const int* __restrict__ incl, const int* __restrict__ bpre,
                      const unsigned char* __restrict__ pks, float* __restrict__ dinv, int E) {
  __shared__ int hist[CB];
  int b = blockIdx.x, tid = threadIdx.x;
  if (tid < CB) hist[tid] = 0;
  __syncthreads();
  int s0 = slotAt(incl, bpre, NCB + b * NBLK) - E;
  int s1 = slotAt(incl, bpre, NCB + (b + 1) * NBLK) - E;
  for (int e = s0 + tid; e < s1; e += 256) atomicAdd(&hist[pks[e]], 1);
  __syncthreads();
  if (tid < CB) {
    int node = b * CB + tid;
    if (node < NN) {
      int c = hist[tid];
      dinv[node] = c > 0 ? rsqrtf((float)c) : 0.f;
    }
  }
}

// ---------------- build P3d: fine sort by dst -> offs + interleaved (src,norm) CSR ----------

__launch_bounds__(256)
__global__ void k_p3d(const int* __restrict__ incl, const int* __restrict__ bpre,
                      const int* __restrict__ pkd, const float* __restrict__ dinv,
                      int* __restrict__ offs, int2* __restrict__ epk, int E) {
  __shared__ int hist[CB], base[CB], cur[CB];
  int b = blockIdx.x, tid = threadIdx.x;
  if (tid < CB) hist[tid] = 0;
  __syncthreads();
  int s0 = slotAt(incl, bpre, b * NBLK);
  int s1 = slotAt(incl, bpre, (b + 1) * NBLK);
  for (int e = s0 + tid; e < s1; e += 256) atomicAdd(&hist[pkd[e] & 127], 1);
  __syncthreads();
  if (tid == 0) {
    int acc = s0;
    for (int i = 0; i < CB; i++) { base[i] = acc; cur[i] = acc; acc += hist[i]; }
  }
  __syncthreads();
  if (tid < CB) {
    int node = b * CB + tid;
    if (node < NN) offs[node] = base[tid];
  }
  if (b == gridDim.x - 1 && tid == 0) offs[NN] = E;
  for (int e = s0 + tid; e < s1; e += 256) {
    int pk = pkd[e];
    int fine = pk & 127, s = pk >> 7;
    int pos = atomicAdd(&cur[fine], 1);
    float nm = dinv[s] * dinv[b * CB + fine];
    epk[pos] = make_int2(s, __float_as_int(nm));
  }
}

// ---------------- weight transpose+convert (merged) ----------------

__global__ void k_wt(const float* __restrict__ W1, const float* __restrict__ W2,
                     unsigned short* __restrict__ W1T, unsigned short* __restrict__ W2T) {
  int idx = blockIdx.x * 256 + threadIdx.x;
  if (idx < HID * KPAD) {
    int n = idx >> 9, k = idx & 511;
    W1T[idx] = (k < CIN) ? f2bf(W1[(long)k * HID + n]) : (unsigned short)0;
  } else if (idx < HID * KPAD + NPADOUT * HID) {
    int i2 = idx - HID * KPAD;
    int n = i2 >> 8, k = i2 & 255;
    W2T[i2] = (n < COUT) ? f2bf(W2[(long)k * COUT + n]) : (unsigned short)0;
  }
}

// ---------------- fused MLP (R5 distance-2 prefetch; R7: HIDB write removed) --------------

#define LOADS(ra0_, ra1_, rb0_, rb1_, kkc)                                        \
  {                                                                               \
    const int kk_ = (kkc);                                                        \
    bool okk = kk_ + sc * 4 <= 496;                                               \
    if (okA && okk) ra0_ = *reinterpret_cast<const float4*>(&X[xbaseA + kk_]);    \
    else { ra0_.x = ra0_.y = ra0_.z = ra0_.w = 0.f; }                             \
    if (okB && okk) ra1_ = *reinterpret_cast<const float4*>(&X[xbaseB + kk_]);    \
    else { ra1_.x = ra1_.y = ra1_.z = ra1_.w = 0.f; }                             \
    rb0_ = *reinterpret_cast<const uint4*>(&W1T[wbase0 + kk_]);                   \
    rb1_ = *reinterpret_cast<const uint4*>(&W1T[wbase1 + kk_]);                   \
  }

#define STORE_LDS(As_, Bs_, ra0_, ra1_, rb0_, rb1_)                               \
  {                                                                               \
    ushort4 v0, v1;                                                               \
    v0.x = f2bf(ra0_.x); v0.y = f2bf(ra0_.y); v0.z = f2bf(ra0_.z); v0.w = f2bf(ra0_.w); \
    v1.x = f2bf(ra1_.x); v1.y = f2bf(ra1_.y); v1.z = f2bf(ra1_.z); v1.w = f2bf(ra1_.w); \
    *reinterpret_cast<ushort4*>(&As_[sr * 40 + sc * 4]) = v0;                     \
    *reinterpret_cast<ushort4*>(&As_[(sr + 64) * 40 + sc * 4]) = v1;              \
    *reinterpret_cast<uint4*>(&Bs_[br * 40 + bc * 8]) = rb0_;                     \
    *reinterpret_cast<uint4*>(&Bs_[(br + 128) * 40 + bc * 8]) = rb1_;             \
  }

#define COMPUTE(As_, Bs_)                                                         \
  {                                                                               \
    short8 af[4], bfr[4];                                                         \
    const int koff = (lane >> 4) * 8;                                             \
    _Pragma("unroll")                                                             \
    for (int i = 0; i < 4; i++)                                                   \
      af[i] = *reinterpret_cast<const short8*>(&As_[(wr * 64 + i * 16 + (lane & 15)) * 40 + koff]); \
    _Pragma("unroll")                                                             \
    for (int j = 0; j < 4; j++)                                                   \
      bfr[j] = *reinterpret_cast<const short8*>(&Bs_[(wc * 64 + j * 16 + (lane & 15)) * 40 + koff]); \
    _Pragma("unroll")                                                             \
    for (int i = 0; i < 4; i++)                                                   \
      _Pragma("unroll")                                                           \
      for (int j = 0; j < 4; j++)                                                 \
        acc[i][j] = __builtin_amdgcn_mfma_f32_16x16x32_bf16(af[i], bfr[j], acc[i][j], 0, 0, 0); \
  }

__launch_bounds__(512)
__global__ void k_mlp(const float* __restrict__ X, const unsigned short* __restrict__ W1T,
                      const float* __restrict__ b1, const unsigned short* __restrict__ W2T,
                      const float* __restrict__ b2, unsigned short* __restrict__ X0B) {
  __shared__ unsigned short smem[2 * 15360];
  const int tid = threadIdx.x;
  const int lane = tid & 63, w = tid >> 6;
  const int wr = w >> 2, wc = w & 3;
  const int row0 = blockIdx.x * 128;
  f32x4 acc[4][4] = {};
  const int sr = tid >> 3, sc = tid & 7;
  const int br = tid >> 2, bc = tid & 3;

  float4 raA0, raA1; uint4 rbA0, rbA1;
  float4 raB0, raB1; uint4 rbB0, rbB1;

  const int growA = row0 + sr;
  const int growB = row0 + sr + 64;
  const bool okA = growA < NN, okB = growB < NN;
  const long xbaseA = (long)growA * CIN + sc * 4;
  const long xbaseB = (long)growB * CIN + sc * 4;
  const long wbase0 = (long)br * KPAD + bc * 8;
  const long wbase1 = (long)(br + 128) * KPAD + bc * 8;

  LOADS(raA0, raA1, rbA0, rbA1, 0);
  LOADS(raB0, raB1, rbB0, rbB1, 32);

#pragma unroll
  for (int tt = 0; tt < 8; tt++) {
    const int kk0 = tt * 64;
    {   // even step: buf0, set A
      unsigned short* As = smem;
      unsigned short* Bs = smem + 128 * 40;
      STORE_LDS(As, Bs, raA0, raA1, rbA0, rbA1);
      __syncthreads();
      if (kk0 + 64 < KPAD) LOADS(raA0, raA1, rbA0, rbA1, kk0 + 64);
      COMPUTE(As, Bs);
    }
    {   // odd step: buf1, set B
      unsigned short* As = smem + 15360;
      unsigned short* Bs = As + 128 * 40;
      STORE_LDS(As, Bs, raB0, raB1, rbB0, rbB1);
      __syncthreads();
      if (kk0 + 96 < KPAD) LOADS(raB0, raB1, rbB0, rbB1, kk0 + 96);
      COMPUTE(As, Bs);
    }
  }

  // ---- epilogue: two 64-row phases through LDS, then h @ W2 ----
  unsigned short* Hs = smem;                    // 64 rows x 264 (stride pad)
  const int rt = w >> 1;
  const int jh = w & 1;
#pragma unroll
  for (int ph = 0; ph < 2; ph++) {
    __syncthreads();
    if (wr == ph) {
#pragma unroll
      for (int i = 0; i < 4; i++) {
        int lr = i * 16 + (lane >> 4) * 4;
#pragma unroll
        for (int j = 0; j < 4; j++) {
          int col = wc * 64 + j * 16 + (lane & 15);
          float bv = b1[col];
#pragma unroll
          for (int r = 0; r < 4; r++) {
            float v = acc[i][j][r] + bv;
            v = v > 0.f ? v : 0.f;
            Hs[(lr + r) * 264 + col] = f2bf(v);
          }
        }
      }
    }
    __syncthreads();
    f32x4 acc2[2] = {};
    const int koff = (lane >> 4) * 8;
    for (int kk = 0; kk < HID; kk += 32) {
      short8 a = *reinterpret_cast<const short8*>(&Hs[(rt * 16 + (lane & 15)) * 264 + kk + koff]);
#pragma unroll
      for (int jj = 0; jj < 2; jj++) {
        int n = (jh * 2 + jj) * 16 + (lane & 15);
        short8 b = *reinterpret_cast<const short8*>(&W2T[n * HID + kk + koff]);
        acc2[jj] = __builtin_amdgcn_mfma_f32_16x16x32_bf16(a, b, acc2[jj], 0, 0, 0);
      }
    }
#pragma unroll
    for (int jj = 0; jj < 2; jj++) {
      int col = (jh * 2 + jj) * 16 + (lane & 15);
      float bv = (col < COUT) ? b2[col] : 0.f;  // W2T pad rows are zero -> v = 0 for pad cols
#pragma unroll
      for (int r = 0; r < 4; r++) {
        int row = row0 + ph * 64 + rt * 16 + (lane >> 4) * 4 + r;
        if (row < NN) {
          float v = acc2[jj][r] + bv;
          X0B[((long)row << 6) + col] = f2bf(v);
        }
      }
    }
  }
}

// ---------------- propagation: 4 nodes/wave, 16 lanes/node, pure gather sweep ----------
// R10 post-mortem of R9 regression (908 vs 826): the nt hints were the poison. xout is
// NOT a single-use stream -- sweep s's xout is sweep s+1's gather table; nt stores made
// the table L2-cold every sweep (+75us). Fix: plain loads/stores again. Kept from R9:
// deferred-hid (k_fin) and k_mlp's removed HIDB write (verified: WRITE_SIZE 32->12.5 MB).
// New: all 16 lanes store a full 8 B -> full 128-B lines, no partial-line RFO on the
// cold rotation buffers. Pads stay exactly 0 inductively (k_mlp zeroes cols 50..63 of
// XB[0]; pad gathers accumulate w*0 = 0 -> f2bf(0) = 0).

__launch_bounds__(256)
__global__ void k_prop(const int* __restrict__ offs, const int2* __restrict__ epk,
                       const unsigned short* __restrict__ xin,
                       unsigned short* __restrict__ xout) {
  const long long* __restrict__ epk8 = reinterpret_cast<const long long*>(epk);
  int node = blockIdx.x * 16 + (threadIdx.x >> 4);
  if (node >= NN) return;
  int h = threadIdx.x & 15;
  int fp = h * 4;                       // first of 4 features (shorts) this lane owns
  int s0 = offs[node], s1 = offs[node + 1];
  float a0 = 0.f, a1 = 0.f, a2 = 0.f, a3 = 0.f;
  int e = s0;
  for (; e + 7 < s1; e += 8) {
    long long p[8];
#pragma unroll
    for (int q = 0; q < 8; q++) p[q] = epk8[e + q];
    uint2 v[8];
#pragma unroll
    for (int q = 0; q < 8; q++)
      v[q] = *reinterpret_cast<const uint2*>(&xin[((long)(int)p[q] << 6) + fp]);
#pragma unroll
    for (int q = 0; q < 8; q++) {
      float wq = __int_as_float((int)(p[q] >> 32));
      a0 += wq * __uint_as_float(v[q].x << 16);
      a1 += wq * __uint_as_float(v[q].x & 0xffff0000u);
      a2 += wq * __uint_as_float(v[q].y << 16);
      a3 += wq * __uint_as_float(v[q].y & 0xffff0000u);
    }
  }
  for (; e + 3 < s1; e += 4) {
    long long p0 = epk8[e], p1 = epk8[e + 1], p2 = epk8[e + 2], p3 = epk8[e + 3];
    uint2 v0 = *reinterpret_cast<const uint2*>(&xin[((long)(int)p0 << 6) + fp]);
    uint2 v1 = *reinterpret_cast<const uint2*>(&xin[((long)(int)p1 << 6) + fp]);
    uint2 v2 = *reinterpret_cast<const uint2*>(&xin[((long)(int)p2 << 6) + fp]);
    uint2 v3 = *reinterpret_cast<const uint2*>(&xin[((long)(int)p3 << 6) + fp]);
    float w0 = __int_as_float((int)(p0 >> 32)), w1 = __int_as_float((int)(p1 >> 32));
    float w2 = __int_as_float((int)(p2 >> 32)), w3 = __int_as_float((int)(p3 >> 32));
    a0 += w0 * __uint_as_float(v0.x << 16) + w1 * __uint_as_float(v1.x << 16)
        + w2 * __uint_as_float(v2.x << 16) + w3 * __uint_as_float(v3.x << 16);
    a1 += w0 * __uint_as_float(v0.x & 0xffff0000u) + w1 * __uint_as_float(v1.x & 0xffff0000u)
        + w2 * __uint_as_float(v2.x & 0xffff0000u) + w3 * __uint_as_float(v3.x & 0xffff0000u);
    a2 += w0 * __uint_as_float(v0.y << 16) + w1 * __uint_as_float(v1.y << 16)
        + w2 * __uint_as_float(v2.y << 16) + w3 * __uint_as_float(v3.y << 16);
    a3 += w0 * __uint_as_float(v0.y & 0xffff0000u) + w1 * __uint_as_float(v1.y & 0xffff0000u)
        + w2 * __uint_as_float(v2.y & 0xffff0000u) + w3 * __uint_as_float(v3.y & 0xffff0000u);
  }
  for (; e < s1; e++) {
    long long p0 = epk8[e];
    float w0 = __int_as_float((int)(p0 >> 32));
    uint2 v0 = *reinterpret_cast<const uint2*>(&xin[((long)(int)p0 << 6) + fp]);
    a0 += w0 * __uint_as_float(v0.x << 16);
    a1 += w0 * __uint_as_float(v0.x & 0xffff0000u);
    a2 += w0 * __uint_as_float(v0.y << 16);
    a3 += w0 * __uint_as_float(v0.y & 0xffff0000u);
  }
  // every lane writes its full 8 B -> whole 128-B row written (no partial-line RFO).
  // lanes with fp >= COUT only ever see zero pads -> store exact zeros.
  unsigned d0 = ((unsigned)f2bf(a1) << 16) | (unsigned)f2bf(a0);
  unsigned d1 = ((unsigned)f2bf(a3) << 16) | (unsigned)f2bf(a2);
  unsigned long long pk8 = ((unsigned long long)d1 << 32) | d0;
  *reinterpret_cast<unsigned long long*>(&xout[((long)node << 6) + fp]) = pk8;
}

// ---------------- final: hidden = sum temp[k]*x_2k, fused log_softmax ----------------

__launch_bounds__(256)
__global__ void k_fin(const unsigned short* __restrict__ x0,
                      const unsigned short* __restrict__ x1,
                      const unsigned short* __restrict__ x2,
                      const unsigned short* __restrict__ x3,
                      const unsigned short* __restrict__ x4,
                      const unsigned short* __restrict__ x5,
                      const float* __restrict__ temp, float* __restrict__ out) {
  int node = blockIdx.x * 4 + (threadIdx.x >> 6);
  if (node >= NN) return;
  int f = threadIdx.x & 63;
  float v = -INFINITY;
  if (f < COUT) {
    long idx = ((long)node << 6) + f;
    v = temp[0] * __uint_as_float((unsigned)x0[idx] << 16)
      + temp[1] * __uint_as_float((unsigned)x1[idx] << 16)
      + temp[2] * __uint_as_float((unsigned)x2[idx] << 16)
      + temp[3] * __uint_as_float((unsigned)x3[idx] << 16)
      + temp[4] * __uint_as_float((unsigned)x4[idx] << 16)
      + temp[5] * __uint_as_float((unsigned)x5[idx] << 16);
  }
  float m = v;
#pragma unroll
  for (int o = 32; o > 0; o >>= 1) m = fmaxf(m, __shfl_xor(m, o, 64));
  float ex = (f < COUT) ? expf(v - m) : 0.f;
  float s = ex;
#pragma unroll
  for (int o = 32; o > 0; o >>= 1) s += __shfl_xor(s, o, 64);
  if (f < COUT) out[(long)node * COUT + f] = (v - m) - logf(s);
}

// ---------------- launch ----------------

extern "C" void kernel_launch(void* const* d_in, const int* in_sizes, int n_in,
                              void* d_out, int out_size, void* d_ws, size_t ws_size,
                              hipStream_t stream) {
  const float* X  = (const float*)d_in[0];
  const int* EI   = (const int*)d_in[1];
  const float* W1 = (const float*)d_in[2];
  const float* B1 = (const float*)d_in[3];
  const float* W2 = (const float*)d_in[4];
  const float* B2 = (const float*)d_in[5];
  const float* TEMP = (const float*)d_in[6];
  const int E = in_sizes[1] / 2;
  const int* src = EI;
  const int* dst = EI + E;

  char* ws = (char*)d_ws;
  size_t off = 0;
  auto alloc = [&](size_t bytes) -> void* {
    off = (off + 511) & ~(size_t)511;
    void* p = ws + off;
    off += bytes;
    return p;
  };
  unsigned short* W1T = (unsigned short*)alloc((size_t)HID * KPAD * 2);
  unsigned short* W2T = (unsigned short*)alloc((size_t)NPADOUT * HID * 2);
  unsigned short* XB[7];                 // XB[0..5] = archived even powers, XB[6] = odd tmp
  for (int i = 0; i < 7; i++) XB[i] = (unsigned short*)alloc((size_t)NN * FPAD * 2);
  float* DINV = (float*)alloc((size_t)NN * 4);
  int* OFFS   = (int*)alloc((size_t)(NN + 1) * 4);
  int* BLKC   = (int*)alloc((size_t)NCB2 * 4);
  int* INCL   = (int*)alloc((size_t)NCB2 * 4);
  int* BSUM   = (int*)alloc(512 * 4);
  int* BPRE   = (int*)alloc(512 * 4);
  int* PKD    = (int*)alloc((size_t)E * 4);
  unsigned char* PKS = (unsigned char*)alloc((size_t)E);
  int2* EPK   = (int2*)alloc((size_t)E * 8);

  const int chunk = (E + NBLK - 1) / NBLK;
  const int nsa = (NCB2 + 1023) / 1024;

  k_p1<<<NBLK, 256, 0, stream>>>(src, dst, BLKC, E, chunk);
  k_scan_a<<<nsa, 256, 0, stream>>>(BLKC, INCL, BSUM, NCB2);
  k_scan_b<<<1, 512, 0, stream>>>(BSUM, BPRE, nsa);
  k_p2<<<NBLK, 256, 0, stream>>>(src, dst, INCL, BPRE, PKD, PKS, E, chunk);
  k_p3s<<<NC, 256, 0, stream>>>(INCL, BPRE, PKS, DINV, E);
  k_p3d<<<NC, 256, 0, stream>>>(INCL, BPRE, PKD, DINV, OFFS, EPK, E);

  k_wt<<<(HID * KPAD + NPADOUT * HID + 255) / 256, 256, 0, stream>>>(W1, W2, W1T, W2T);

  k_mlp<<<(NN + 127) / 128, 512, 0, stream>>>(X, W1T, B1, W2T, B2, XB[0]);

  const int PB = (NN + 15) / 16;
  for (int k = 0; k < 5; k++) {
    k_prop<<<PB, 256, 0, stream>>>(OFFS, EPK, XB[k], XB[6]);
    k_prop<<<PB, 256, 0, stream>>>(OFFS, EPK, XB[6], XB[k + 1]);
  }
  k_fin<<<(NN + 3) / 4, 256, 0, stream>>>(XB[0], XB[1], XB[2], XB[3], XB[4], XB[5],
                                          TEMP, (float*)d_out);
}